// Round 1
// baseline (356.115 us; speedup 1.0000x reference)
//
#include <hip/hip_runtime.h>

// Signed distance transform, N=192^3, exact separable EDT.
// Pass structure:
//   axis 0: binary run-length scan (both fields, reads x once)
//   axis 1: brute-force min-plus, LDS-tiled (64 lines x 192 elems)
//   axis 2: brute-force min-plus, LDS-tiled
//   combine: tanh((sqrt(A)-sqrt(B))/10)
// Field A (dist^2 to x==0) lives in d_ws, field B (dist^2 to x!=0) in d_out.

#define NN   192
#define NN2  (192 * 192)       // 36864
#define NN3  (192 * 192 * 192) // 7077888
#define FINF 1.0e8f

// ---------------------------------------------------------------------------
// Pass 1 (axis 0, stride NN2): binary input -> squared run-length distances.
// One thread per line; coalesced (lanes = consecutive lines, contiguous base).
// Backward scan stores next-seed run length (u8) in LDS, forward scan combines.
// ---------------------------------------------------------------------------
__global__ __launch_bounds__(128) void sdt_scan_axis0(const float* __restrict__ x,
                                                      float* __restrict__ A,
                                                      float* __restrict__ B) {
    __shared__ unsigned char nxF[NN * 128]; // 24 KiB
    __shared__ unsigned char nxB[NN * 128]; // 24 KiB
    const int t = threadIdx.x;
    const int L = blockIdx.x * 128 + t; // line id in [0, NN2)

    unsigned int runF = 250u, runB = 250u;
    for (int i = NN - 1; i >= 0; --i) {
        float v = x[(size_t)L + (size_t)i * NN2];
        bool fg = (v != 0.0f);
        runB = fg ? 0u : (runB < 250u ? runB + 1u : 250u);
        runF = fg ? (runF < 250u ? runF + 1u : 250u) : 0u;
        nxB[i * 128 + t] = (unsigned char)runB;
        nxF[i * 128 + t] = (unsigned char)runF;
    }
    // each thread only touches its own LDS bytes -> no barrier needed
    unsigned int rpF = 250u, rpB = 250u;
    for (int i = 0; i < NN; ++i) {
        unsigned int nB = nxB[i * 128 + t];
        unsigned int nF = nxF[i * 128 + t];
        rpB = (nB == 0u) ? 0u : (rpB < 250u ? rpB + 1u : 250u);
        rpF = (nF == 0u) ? 0u : (rpF < 250u ? rpF + 1u : 250u);
        unsigned int dB = rpB < nB ? rpB : nB;
        unsigned int dF = rpF < nF ? rpF : nF;
        float d2B = (dB >= 250u) ? FINF : (float)(dB * dB);
        float d2F = (dF >= 250u) ? FINF : (float)(dF * dF);
        A[(size_t)L + (size_t)i * NN2] = d2F;
        B[(size_t)L + (size_t)i * NN2] = d2B;
    }
}

// ---------------------------------------------------------------------------
// Brute-force 1D min-plus on a 64-line x 192-elem LDS tile.
// lds layout: lds[j*65 + l]  (pad 65 -> conflict-free writes, broadcast reads)
// On entry lds holds g[j] = f[j] + j^2; on exit it holds d[i] (output).
// Wave w owns lines l = w*16 .. w*16+15; lane handles outputs i, i+64, i+128.
// d[i] = i^2 + min_j (g[j] - 2*i*j)   -- exact for integer-valued g < 2^18.
// ---------------------------------------------------------------------------
__device__ __forceinline__ void brute_tile_compute(float* lds) {
    const int lane = threadIdx.x & 63;
    const int w    = threadIdx.x >> 6;
    const float fi0 = (float)lane;
    const float fi1 = (float)(lane + 64);
    const float fi2 = (float)(lane + 128);
    const float n0 = -2.0f * fi0, n1 = -2.0f * fi1, n2 = -2.0f * fi2;
    const float c0 = fi0 * fi0, c1 = fi1 * fi1, c2 = fi2 * fi2;

    for (int s = 0; s < 16; ++s) {
        const int l = w * 16 + s;
        const float* col = lds + l;
        float d0 = 1e30f, d1 = 1e30f, d2 = 1e30f;
        float jf = 0.0f;
#pragma unroll 8
        for (int j = 0; j < NN; j += 2) {
            float g0 = col[j * 65];
            float g1 = col[(j + 1) * 65];
            float ja = jf, jb = jf + 1.0f;
            float t00 = fmaf(ja, n0, g0), t01 = fmaf(jb, n0, g1);
            float t10 = fmaf(ja, n1, g0), t11 = fmaf(jb, n1, g1);
            float t20 = fmaf(ja, n2, g0), t21 = fmaf(jb, n2, g1);
            d0 = fminf(fminf(d0, t00), t01);
            d1 = fminf(fminf(d1, t10), t11);
            d2 = fminf(fminf(d2, t20), t21);
            jf += 2.0f;
        }
        // column l fully consumed by this wave before these writes (in-order DS)
        lds[lane * 65 + l]         = d0 + c0;
        lds[(lane + 64) * 65 + l]  = d1 + c1;
        lds[(lane + 128) * 65 + l] = d2 + c2;
    }
}

// ---------------------------------------------------------------------------
// Axis-1 pass (elem stride NN, lines contiguous).
// group g: outer i = g/3, k0 = (g%3)*64; base = i*NN2 + k0; line l at base+l.
// ---------------------------------------------------------------------------
__global__ __launch_bounds__(256) void sdt_pass_axis1(float* __restrict__ f) {
    __shared__ float lds[NN * 65]; // 49920 B
    const int g = blockIdx.x;
    const size_t base = (size_t)(g / 3) * NN2 + (size_t)(g % 3) * 64;

    for (int idx = threadIdx.x; idx < NN * 64; idx += 256) {
        const int j = idx >> 6, l = idx & 63;
        float v = f[base + (size_t)j * NN + l];
        lds[j * 65 + l] = v + (float)(j * j);
    }
    __syncthreads();
    brute_tile_compute(lds);
    __syncthreads();
    for (int idx = threadIdx.x; idx < NN * 64; idx += 256) {
        const int j = idx >> 6, l = idx & 63;
        f[base + (size_t)j * NN + l] = lds[j * 65 + l];
    }
}

// ---------------------------------------------------------------------------
// Axis-2 pass (contiguous lines, line stride NN).
// group g: 64 consecutive rows, base = g*64*NN.
// ---------------------------------------------------------------------------
__global__ __launch_bounds__(256) void sdt_pass_axis2(float* __restrict__ f) {
    __shared__ float lds[NN * 65];
    const size_t base = (size_t)blockIdx.x * (64 * NN);

    for (int idx = threadIdx.x; idx < NN * 64; idx += 256) {
        const int l = idx / NN;
        const int j = idx - l * NN;
        float v = f[base + idx];
        lds[j * 65 + l] = v + (float)(j * j);
    }
    __syncthreads();
    brute_tile_compute(lds);
    __syncthreads();
    for (int idx = threadIdx.x; idx < NN * 64; idx += 256) {
        const int l = idx / NN;
        const int j = idx - l * NN;
        f[base + idx] = lds[j * 65 + l];
    }
}

// ---------------------------------------------------------------------------
// Combine: out = tanh((sqrt(A) - sqrt(B)) / 10), B read from d_out in place.
// ---------------------------------------------------------------------------
__global__ __launch_bounds__(256) void sdt_combine(const float* __restrict__ A,
                                                   float* __restrict__ out) {
    const int idx = blockIdx.x * 256 + threadIdx.x;
    if (idx < NN3 / 4) {
        const float4* a4 = (const float4*)A;
        float4* o4 = (float4*)out;
        float4 a = a4[idx];
        float4 b = o4[idx];
        float4 r;
        r.x = tanhf((sqrtf(a.x) - sqrtf(b.x)) * 0.1f);
        r.y = tanhf((sqrtf(a.y) - sqrtf(b.y)) * 0.1f);
        r.z = tanhf((sqrtf(a.z) - sqrtf(b.z)) * 0.1f);
        r.w = tanhf((sqrtf(a.w) - sqrtf(b.w)) * 0.1f);
        o4[idx] = r;
    }
}

extern "C" void kernel_launch(void* const* d_in, const int* in_sizes, int n_in,
                              void* d_out, int out_size, void* d_ws, size_t ws_size,
                              hipStream_t stream) {
    const float* x = (const float*)d_in[0];
    float* A = (float*)d_ws;   // dist^2 to nearest zero of x   (needs 28.3 MB)
    float* B = (float*)d_out;  // dist^2 to nearest nonzero of x

    sdt_scan_axis0<<<NN2 / 128, 128, 0, stream>>>(x, A, B);
    sdt_pass_axis1<<<576, 256, 0, stream>>>(A);
    sdt_pass_axis1<<<576, 256, 0, stream>>>(B);
    sdt_pass_axis2<<<576, 256, 0, stream>>>(A);
    sdt_pass_axis2<<<576, 256, 0, stream>>>(B);
    sdt_combine<<<(NN3 / 4 + 255) / 256, 256, 0, stream>>>(A, B);
}

// Round 2
// 195.245 us; speedup vs baseline: 1.8239x; 1.8239x over previous
//
#include <hip/hip_runtime.h>

// Signed distance transform, N=192^3, exact separable EDT.
//   axis 0: binary run-length scan (both fields, reads x once)
//   axis 1/2: BANDED min-plus. Per line, a shuffle-based prefix/suffix min in
//             sqrt-domain gives K >= sqrt(d(i)) for all i; search j in
//             [i-K, i+K+1] over a sentinel-padded LDS tile. K>40 -> full loop.
//   combine (tanh((sqrt(A)-sqrt(B))/10)) fused into B's axis-2 pass.
// Field A (dist^2 to x==0) in d_ws, field B (dist^2 to x!=0) in d_out.

#define NN   192
#define NN2  (192 * 192)
#define NN3  (192 * 192 * 192)
#define FINF 1.0e8f

#define LINES 48          // lines per block tile
#define SLD   49          // LDS line stride (49 % 32 = 17, odd -> 2-way max)
#define PADR  40          // sentinel rows in front (41 in back)
#define ROWS  273         // 40 + 192 + 41
#define SENT  3.0e7f      // sentinel value: never wins vs real (<2e5)

// ---------------------------------------------------------------------------
// Pass 1 (axis 0, stride NN2): binary input -> squared run-length distances.
// ---------------------------------------------------------------------------
__global__ __launch_bounds__(128) void sdt_scan_axis0(const float* __restrict__ x,
                                                      float* __restrict__ A,
                                                      float* __restrict__ B) {
    __shared__ unsigned char nxF[NN * 128];
    __shared__ unsigned char nxB[NN * 128];
    const int t = threadIdx.x;
    const int L = blockIdx.x * 128 + t;

    unsigned int runF = 250u, runB = 250u;
    for (int i = NN - 1; i >= 0; --i) {
        float v = x[(size_t)L + (size_t)i * NN2];
        bool fg = (v != 0.0f);
        runB = fg ? 0u : (runB < 250u ? runB + 1u : 250u);
        runF = fg ? (runF < 250u ? runF + 1u : 250u) : 0u;
        nxB[i * 128 + t] = (unsigned char)runB;
        nxF[i * 128 + t] = (unsigned char)runF;
    }
    unsigned int rpF = 250u, rpB = 250u;
    for (int i = 0; i < NN; ++i) {
        unsigned int nB = nxB[i * 128 + t];
        unsigned int nF = nxF[i * 128 + t];
        rpB = (nB == 0u) ? 0u : (rpB < 250u ? rpB + 1u : 250u);
        rpF = (nF == 0u) ? 0u : (rpF < 250u ? rpF + 1u : 250u);
        unsigned int dB = rpB < nB ? rpB : nB;
        unsigned int dF = rpF < nF ? rpF : nF;
        A[(size_t)L + (size_t)i * NN2] = (dF >= 250u) ? FINF : (float)(dF * dF);
        B[(size_t)L + (size_t)i * NN2] = (dB >= 250u) ? FINF : (float)(dB * dB);
    }
}

// ---------------------------------------------------------------------------
// Banded min-plus pass. AXIS=1: elems stride NN, lines contiguous.
// AXIS=2: elems contiguous, lines stride NN. FUSE: tanh epilogue (AXIS=2 only).
// ---------------------------------------------------------------------------
template<int AXIS, bool FUSE>
__global__ __launch_bounds__(256) void sdt_pass(float* __restrict__ f,
                                                const float* __restrict__ other,
                                                float* __restrict__ outp) {
    __shared__ float lds[ROWS * SLD]; // 53,508 B

    const int tid = threadIdx.x;
    const int g = blockIdx.x;
    size_t base;
    if (AXIS == 1) base = (size_t)(g >> 2) * NN2 + (size_t)(g & 3) * LINES;
    else           base = (size_t)g * (LINES * NN);

    // sentinel rows: [0,40) and [232,273)
    for (int idx = tid; idx < 81 * SLD; idx += 256) {
        int r = idx / SLD, c = idx - r * SLD;
        int row = r < PADR ? r : r + NN;
        lds[row * SLD + c] = SENT;
    }
    // stage in: G[j][l] = f + j^2
    if (AXIS == 1) {
        for (int idx = tid; idx < NN * LINES / 2; idx += 256) {
            int j = idx / (LINES / 2), lp = idx - j * (LINES / 2);
            float2 v = *(const float2*)(f + base + (size_t)j * NN + 2 * lp);
            float jj = (float)(j * j);
            int a = (PADR + j) * SLD + 2 * lp;
            lds[a] = v.x + jj;
            lds[a + 1] = v.y + jj;
        }
    } else {
        for (int idx = tid; idx < NN * LINES / 2; idx += 256) {
            int l = idx / (NN / 2), jp = idx - l * (NN / 2);
            int j = 2 * jp;
            float2 v = *(const float2*)(f + base + (size_t)l * NN + j);
            int a = (PADR + j) * SLD + l;
            lds[a] = v.x + (float)(j * j);
            lds[a + SLD] = v.y + (float)((j + 1) * (j + 1));
        }
    }
    __syncthreads();

    const int lane = tid & 63;
    const int w = tid >> 6;

    for (int sL = 0; sL < LINES / 4; ++sL) {
        const int l = w * (LINES / 4) + sL;
        const float* col = lds + l;

        // ---- band-width scan: K >= sqrt(d(i)) for all i of this line ----
        const int ib = 3 * lane;
        const float fi = (float)ib;
        float G0 = col[(PADR + ib) * SLD];
        float G1 = col[(PADR + ib + 1) * SLD];
        float G2 = col[(PADR + ib + 2) * SLD];
        float s0 = sqrtf(G0 - (float)(ib * ib));
        float s1 = sqrtf(G1 - (float)((ib + 1) * (ib + 1)));
        float s2 = sqrtf(G2 - (float)((ib + 2) * (ib + 2)));
        // forward: m_f(i) = i + prefmin(s_j - j)
        float a0 = s0 - fi, a1 = s1 - (fi + 1.f), a2 = s2 - (fi + 2.f);
        float p1 = fminf(a1, a0), p2 = fminf(a2, p1);
        float P = p2;
#pragma unroll
        for (int dd = 1; dd < 64; dd <<= 1) {
            float o = __shfl_up(P, dd, 64);
            P = (lane >= dd) ? fminf(P, o) : P;
        }
        float E = __shfl_up(P, 1, 64);
        if (lane == 0) E = 1e30f;
        float mf0 = fi + fminf(a0, E);
        float mf1 = (fi + 1.f) + fminf(p1, E);
        float mf2 = (fi + 2.f) + fminf(p2, E);
        // backward: m_b(i) = -i + sufmin(s_j + j)
        float b0 = s0 + fi, b1 = s1 + (fi + 1.f), b2 = s2 + (fi + 2.f);
        float q1 = fminf(b1, b2), q0 = fminf(b0, q1);
        float Q = q0;
#pragma unroll
        for (int dd = 1; dd < 64; dd <<= 1) {
            float o = __shfl_down(Q, dd, 64);
            Q = (lane < 64 - dd) ? fminf(Q, o) : Q;
        }
        float F = __shfl_down(Q, 1, 64);
        if (lane == 63) F = 1e30f;
        float mb0 = fminf(q0, F) - fi;
        float mb1 = fminf(q1, F) - (fi + 1.f);
        float mb2 = fminf(b2, F) - (fi + 2.f);

        float km = fmaxf(fminf(mf0, mb0), fmaxf(fminf(mf1, mb1), fminf(mf2, mb2)));
#pragma unroll
        for (int dd = 1; dd < 64; dd <<= 1) km = fmaxf(km, __shfl_xor(km, dd, 64));
        int K = (int)ceilf(km) + 1;
        K = __builtin_amdgcn_readfirstlane(K);

        // ---- min-plus over band (or full fallback) ----
        const int i1 = lane + 64, i2 = lane + 128;
        const float n0 = -2.f * (float)lane, n1 = -2.f * (float)i1, n2 = -2.f * (float)i2;
        float d0 = 3e38f, d1 = 3e38f, d2 = 3e38f;

        if (K <= PADR) {
            int a0i = (PADR + lane - K) * SLD + l;
            int a1i = a0i + 64 * SLD, a2i = a1i + 64 * SLD;
            float jf = (float)(lane - K);
            for (int t = 0; t <= K; ++t) {
                float g00 = lds[a0i], g01 = lds[a0i + SLD];
                float g10 = lds[a1i], g11 = lds[a1i + SLD];
                float g20 = lds[a2i], g21 = lds[a2i + SLD];
                d0 = fminf(d0, fmaf(jf, n0, g00));
                d0 = fminf(d0, fmaf(jf + 1.f, n0, g01));
                d1 = fminf(d1, fmaf(jf + 64.f, n1, g10));
                d1 = fminf(d1, fmaf(jf + 65.f, n1, g11));
                d2 = fminf(d2, fmaf(jf + 128.f, n2, g20));
                d2 = fminf(d2, fmaf(jf + 129.f, n2, g21));
                jf += 2.f;
                a0i += 2 * SLD; a1i += 2 * SLD; a2i += 2 * SLD;
            }
        } else {
            int ai = PADR * SLD + l;
            float jf = 0.f;
            for (int t = 0; t < NN / 2; ++t) {
                float g0 = lds[ai], g1 = lds[ai + SLD];
                float jb = jf + 1.f;
                d0 = fminf(d0, fmaf(jf, n0, g0)); d0 = fminf(d0, fmaf(jb, n0, g1));
                d1 = fminf(d1, fmaf(jf, n1, g0)); d1 = fminf(d1, fmaf(jb, n1, g1));
                d2 = fminf(d2, fmaf(jf, n2, g0)); d2 = fminf(d2, fmaf(jb, n2, g1));
                jf += 2.f;
                ai += 2 * SLD;
            }
        }
        // column l fully consumed by this wave; column-local writes are safe
        lds[(PADR + lane) * SLD + l] = d0 + (float)(lane * lane);
        lds[(PADR + i1) * SLD + l]   = d1 + (float)(i1 * i1);
        lds[(PADR + i2) * SLD + l]   = d2 + (float)(i2 * i2);
    }
    __syncthreads();

    // ---- stage out ----
    if (!FUSE) {
        if (AXIS == 1) {
            for (int idx = tid; idx < NN * LINES / 2; idx += 256) {
                int j = idx / (LINES / 2), lp = idx - j * (LINES / 2);
                int a = (PADR + j) * SLD + 2 * lp;
                float2 v;
                v.x = lds[a];
                v.y = lds[a + 1];
                *(float2*)(f + base + (size_t)j * NN + 2 * lp) = v;
            }
        } else {
            for (int idx = tid; idx < NN * LINES / 2; idx += 256) {
                int l = idx / (NN / 2), jp = idx - l * (NN / 2);
                int j = 2 * jp;
                int a = (PADR + j) * SLD + l;
                float2 v;
                v.x = lds[a];
                v.y = lds[a + SLD];
                *(float2*)(f + base + (size_t)l * NN + j) = v;
            }
        }
    } else {
        // fused combine: out = tanh((sqrt(A) - sqrt(B)) / 10)
        for (int idx = tid; idx < NN * LINES / 2; idx += 256) {
            int l = idx / (NN / 2), jp = idx - l * (NN / 2);
            int j = 2 * jp;
            int a = (PADR + j) * SLD + l;
            float bb0 = lds[a], bb1 = lds[a + SLD];
            size_t ga = base + (size_t)l * NN + j;
            float2 av = *(const float2*)(other + ga);
            float x0 = (sqrtf(av.x) - sqrtf(bb0)) * 0.1f;
            float x1 = (sqrtf(av.y) - sqrtf(bb1)) * 0.1f;
            float e0 = __expf(2.f * x0);
            float e1 = __expf(2.f * x1);
            float2 r;
            r.x = 1.f - 2.f * __builtin_amdgcn_rcpf(e0 + 1.f);
            r.y = 1.f - 2.f * __builtin_amdgcn_rcpf(e1 + 1.f);
            *(float2*)(outp + ga) = r;
        }
    }
}

extern "C" void kernel_launch(void* const* d_in, const int* in_sizes, int n_in,
                              void* d_out, int out_size, void* d_ws, size_t ws_size,
                              hipStream_t stream) {
    const float* x = (const float*)d_in[0];
    float* A = (float*)d_ws;   // dist^2 to nearest zero of x
    float* B = (float*)d_out;  // dist^2 to nearest nonzero of x
    float* out = (float*)d_out;

    sdt_scan_axis0<<<NN2 / 128, 128, 0, stream>>>(x, A, B);
    sdt_pass<1, false><<<768, 256, 0, stream>>>(A, nullptr, nullptr);
    sdt_pass<2, false><<<768, 256, 0, stream>>>(A, nullptr, nullptr);
    sdt_pass<1, false><<<768, 256, 0, stream>>>(B, nullptr, nullptr);
    sdt_pass<2, true ><<<768, 256, 0, stream>>>(B, A, out);
}

// Round 3
// 163.315 us; speedup vs baseline: 2.1805x; 1.1955x over previous
//
#include <hip/hip_runtime.h>

// Signed distance transform, N=192^3, exact separable EDT.
//   axis 0: binary run-length scan (both fields, reads x once)
//   axis 1/2: banded min-plus, line-major LDS tile, ONE shared band bound per
//             wave (12 lines) from the pointwise-max profile; contiguous b128
//             band reads; K>37 -> full loop. Fused tanh epilogue on last pass.
// Field A (dist^2 to x==0) in d_ws, field B (dist^2 to x!=0) in d_out.

#define NN    192
#define NN2   (192 * 192)
#define NN3   (192 * 192 * 192)
#define FINF  1.0e8f

#define LINES 48
#define PADL  40
#define SROW  276        // 40 pad + 192 data + 44 pad; %4==0 keeps b128 aligned
#define KBAND 37         // band path limit (fits pads: j in [-40, 235])
#define SENT  3.0e7f     // sentinel: never beats real candidates (<1.2e5)

// ---------------------------------------------------------------------------
// Pass 1 (axis 0, stride NN2): binary input -> squared run-length distances.
// ---------------------------------------------------------------------------
__global__ __launch_bounds__(128) void sdt_scan_axis0(const float* __restrict__ x,
                                                      float* __restrict__ A,
                                                      float* __restrict__ B) {
    __shared__ unsigned char nxF[NN * 128];
    __shared__ unsigned char nxB[NN * 128];
    const int t = threadIdx.x;
    const int L = blockIdx.x * 128 + t;

    unsigned int runF = 250u, runB = 250u;
    for (int i = NN - 1; i >= 0; --i) {
        float v = x[(size_t)L + (size_t)i * NN2];
        bool fg = (v != 0.0f);
        runB = fg ? 0u : (runB < 250u ? runB + 1u : 250u);
        runF = fg ? (runF < 250u ? runF + 1u : 250u) : 0u;
        nxB[i * 128 + t] = (unsigned char)runB;
        nxF[i * 128 + t] = (unsigned char)runF;
    }
    unsigned int rpF = 250u, rpB = 250u;
    for (int i = 0; i < NN; ++i) {
        unsigned int nB = nxB[i * 128 + t];
        unsigned int nF = nxF[i * 128 + t];
        rpB = (nB == 0u) ? 0u : (rpB < 250u ? rpB + 1u : 250u);
        rpF = (nF == 0u) ? 0u : (rpF < 250u ? rpF + 1u : 250u);
        unsigned int dB = rpB < nB ? rpB : nB;
        unsigned int dF = rpF < nF ? rpF : nF;
        A[(size_t)L + (size_t)i * NN2] = (dF >= 250u) ? FINF : (float)(dF * dF);
        B[(size_t)L + (size_t)i * NN2] = (dB >= 250u) ? FINF : (float)(dB * dB);
    }
}

// ---------------------------------------------------------------------------
// Banded min-plus pass, line-major tile.
// AXIS=1: elems stride NN (j), lines contiguous (l). Grid 1536: g<768 -> A.
// AXIS=2: elems contiguous (j), lines stride NN (l). FUSE: tanh epilogue.
// ---------------------------------------------------------------------------
template<int AXIS, bool FUSE>
__global__ __launch_bounds__(256) void sdt_pass(float* __restrict__ fA,
                                                float* __restrict__ fB,
                                                const float* __restrict__ other,
                                                float* __restrict__ outp) {
    __shared__ __align__(16) float lds[LINES * SROW]; // 52,992 B -> 3 blocks/CU

    const int tid = threadIdx.x;
    int g = blockIdx.x;
    float* f = fA;
    if (AXIS == 1 && g >= 768) { f = fB; g -= 768; }

    size_t base;
    if (AXIS == 1) base = (size_t)(g >> 2) * NN2 + (size_t)(g & 3) * LINES;
    else           base = (size_t)g * (LINES * NN);

    // sentinel pads: words [0,40) and [232,276) of each line
    for (int idx = tid; idx < LINES * 84; idx += 256) {
        int l = idx / 84, c = idx - l * 84;
        int word = (c < PADL) ? c : (c + NN);
        lds[l * SROW + word] = SENT;
    }
    // stage in: G[l][j] = f + j^2
    if (AXIS == 1) {
        for (int idx = tid; idx < NN * LINES / 2; idx += 256) {
            int j = idx / (LINES / 2), lp = idx - j * (LINES / 2);
            float2 v = *(const float2*)(f + base + (size_t)j * NN + 2 * lp);
            float jj = (float)(j * j);
            lds[(2 * lp) * SROW + PADL + j]     = v.x + jj;
            lds[(2 * lp + 1) * SROW + PADL + j] = v.y + jj;
        }
    } else {
        for (int idx = tid; idx < NN * LINES / 4; idx += 256) {
            int l = idx / (NN / 4), jp = idx - l * (NN / 4);
            float4 v = *(const float4*)(f + base + (size_t)l * NN + 4 * jp);
            int j = 4 * jp;
            float4 gq;
            gq.x = v.x + (float)(j * j);
            gq.y = v.y + (float)((j + 1) * (j + 1));
            gq.z = v.z + (float)((j + 2) * (j + 2));
            gq.w = v.w + (float)((j + 3) * (j + 3));
            *(float4*)(lds + l * SROW + PADL + j) = gq;
        }
    }
    __syncthreads();

    const int lane = tid & 63;
    const int w = tid >> 6;
    const int l0 = w * (LINES / 4); // 12 lines per wave

    // ---- ONE shared band bound per wave: scan pointwise-max profile ----
    const int ib = 3 * lane;
    float M0 = 0.f, M1 = 0.f, M2 = 0.f;
    {
        const float* r = lds + l0 * SROW + PADL;
#pragma unroll
        for (int t = 0; t < LINES / 4; ++t) {
            M0 = fmaxf(M0, r[ib]);
            M1 = fmaxf(M1, r[ib + 1]);
            M2 = fmaxf(M2, r[ib + 2]);
            r += SROW;
        }
    }
    const float fi = (float)ib;
    float s0 = sqrtf(M0 - fi * fi);
    float s1 = sqrtf(M1 - (fi + 1.f) * (fi + 1.f));
    float s2 = sqrtf(M2 - (fi + 2.f) * (fi + 2.f));
    float a0 = s0 - fi, a1 = s1 - (fi + 1.f), a2 = s2 - (fi + 2.f);
    float p1 = fminf(a1, a0), p2 = fminf(a2, p1);
    float P = p2;
#pragma unroll
    for (int dd = 1; dd < 64; dd <<= 1) {
        float o = __shfl_up(P, dd, 64);
        P = (lane >= dd) ? fminf(P, o) : P;
    }
    float E = __shfl_up(P, 1, 64);
    if (lane == 0) E = 1e30f;
    float mf0 = fi + fminf(a0, E);
    float mf1 = (fi + 1.f) + fminf(p1, E);
    float mf2 = (fi + 2.f) + fminf(p2, E);
    float b0 = s0 + fi, b1 = s1 + (fi + 1.f), b2 = s2 + (fi + 2.f);
    float q1 = fminf(b1, b2), q0 = fminf(b0, q1);
    float Q = q0;
#pragma unroll
    for (int dd = 1; dd < 64; dd <<= 1) {
        float o = __shfl_down(Q, dd, 64);
        Q = (lane < 64 - dd) ? fminf(Q, o) : Q;
    }
    float F = __shfl_down(Q, 1, 64);
    if (lane == 63) F = 1e30f;
    float mb0 = fminf(q0, F) - fi;
    float mb1 = fminf(q1, F) - (fi + 1.f);
    float mb2 = fminf(b2, F) - (fi + 2.f);
    float km = fmaxf(fminf(mf0, mb0), fmaxf(fminf(mf1, mb1), fminf(mf2, mb2)));
#pragma unroll
    for (int dd = 1; dd < 64; dd <<= 1) km = fmaxf(km, __shfl_xor(km, dd, 64));
    int K = (int)ceilf(km) + 1;
    K = __builtin_amdgcn_readfirstlane(K);

    const int i1 = lane + 64, i2 = lane + 128;
    const float n0 = -2.f * (float)lane, n1 = -2.f * (float)i1, n2 = -2.f * (float)i2;
    const float c0 = (float)(lane * lane), c1 = (float)(i1 * i1), c2 = (float)(i2 * i2);

    if (K <= KBAND) {
        const int s0w = (lane - K) & ~3;
        const int nw = (2 * K + 8) >> 2;
        float* row = lds + l0 * SROW + PADL;
        for (int t = 0; t < LINES / 4; ++t) {
            const float* p = row + s0w;
            float d0 = 3e38f, d1 = 3e38f, d2 = 3e38f;
            float jf = (float)s0w;
            for (int u = 0; u < nw; ++u) {
                float4 ga = *(const float4*)(p);
                float4 gb = *(const float4*)(p + 64);
                float4 gc = *(const float4*)(p + 128);
                d0 = fminf(d0, fmaf(jf,        n0, ga.x));
                d0 = fminf(d0, fmaf(jf + 1.f,  n0, ga.y));
                d0 = fminf(d0, fmaf(jf + 2.f,  n0, ga.z));
                d0 = fminf(d0, fmaf(jf + 3.f,  n0, ga.w));
                d1 = fminf(d1, fmaf(jf + 64.f, n1, gb.x));
                d1 = fminf(d1, fmaf(jf + 65.f, n1, gb.y));
                d1 = fminf(d1, fmaf(jf + 66.f, n1, gb.z));
                d1 = fminf(d1, fmaf(jf + 67.f, n1, gb.w));
                d2 = fminf(d2, fmaf(jf + 128.f, n2, gc.x));
                d2 = fminf(d2, fmaf(jf + 129.f, n2, gc.y));
                d2 = fminf(d2, fmaf(jf + 130.f, n2, gc.z));
                d2 = fminf(d2, fmaf(jf + 131.f, n2, gc.w));
                p += 4; jf += 4.f;
            }
            // this wave owns these lines; reads of line t are done (in-order DS)
            row[lane] = d0 + c0;
            row[i1]   = d1 + c1;
            row[i2]   = d2 + c2;
            row += SROW;
        }
    } else {
        float* row = lds + l0 * SROW + PADL;
        for (int t = 0; t < LINES / 4; ++t) {
            const float4* p = (const float4*)row;
            float d0 = 3e38f, d1 = 3e38f, d2 = 3e38f;
            float jf = 0.f;
            for (int u = 0; u < NN / 4; ++u) {
                float4 gv = p[u];
                d0 = fminf(d0, fmaf(jf,       n0, gv.x));
                d0 = fminf(d0, fmaf(jf + 1.f, n0, gv.y));
                d0 = fminf(d0, fmaf(jf + 2.f, n0, gv.z));
                d0 = fminf(d0, fmaf(jf + 3.f, n0, gv.w));
                d1 = fminf(d1, fmaf(jf,       n1, gv.x));
                d1 = fminf(d1, fmaf(jf + 1.f, n1, gv.y));
                d1 = fminf(d1, fmaf(jf + 2.f, n1, gv.z));
                d1 = fminf(d1, fmaf(jf + 3.f, n1, gv.w));
                d2 = fminf(d2, fmaf(jf,       n2, gv.x));
                d2 = fminf(d2, fmaf(jf + 1.f, n2, gv.y));
                d2 = fminf(d2, fmaf(jf + 2.f, n2, gv.z));
                d2 = fminf(d2, fmaf(jf + 3.f, n2, gv.w));
                jf += 4.f;
            }
            row[lane] = d0 + c0;
            row[i1]   = d1 + c1;
            row[i2]   = d2 + c2;
            row += SROW;
        }
    }
    __syncthreads();

    // ---- stage out ----
    if (AXIS == 1) {
        for (int idx = tid; idx < NN * LINES / 2; idx += 256) {
            int j = idx / (LINES / 2), lp = idx - j * (LINES / 2);
            float2 v;
            v.x = lds[(2 * lp) * SROW + PADL + j];
            v.y = lds[(2 * lp + 1) * SROW + PADL + j];
            *(float2*)(f + base + (size_t)j * NN + 2 * lp) = v;
        }
    } else if (!FUSE) {
        for (int idx = tid; idx < NN * LINES / 4; idx += 256) {
            int l = idx / (NN / 4), jp = idx - l * (NN / 4);
            float4 v = *(const float4*)(lds + l * SROW + PADL + 4 * jp);
            *(float4*)(f + base + (size_t)l * NN + 4 * jp) = v;
        }
    } else {
        for (int idx = tid; idx < NN * LINES / 4; idx += 256) {
            int l = idx / (NN / 4), jp = idx - l * (NN / 4);
            float4 bv = *(const float4*)(lds + l * SROW + PADL + 4 * jp);
            size_t ga = base + (size_t)l * NN + 4 * jp;
            float4 av = *(const float4*)(other + ga);
            float4 r;
            {
                float xx = (sqrtf(av.x) - sqrtf(bv.x)) * 0.1f;
                float e = __expf(2.f * xx);
                r.x = 1.f - 2.f * __builtin_amdgcn_rcpf(e + 1.f);
            }
            {
                float xx = (sqrtf(av.y) - sqrtf(bv.y)) * 0.1f;
                float e = __expf(2.f * xx);
                r.y = 1.f - 2.f * __builtin_amdgcn_rcpf(e + 1.f);
            }
            {
                float xx = (sqrtf(av.z) - sqrtf(bv.z)) * 0.1f;
                float e = __expf(2.f * xx);
                r.z = 1.f - 2.f * __builtin_amdgcn_rcpf(e + 1.f);
            }
            {
                float xx = (sqrtf(av.w) - sqrtf(bv.w)) * 0.1f;
                float e = __expf(2.f * xx);
                r.w = 1.f - 2.f * __builtin_amdgcn_rcpf(e + 1.f);
            }
            *(float4*)(outp + ga) = r;
        }
    }
}

extern "C" void kernel_launch(void* const* d_in, const int* in_sizes, int n_in,
                              void* d_out, int out_size, void* d_ws, size_t ws_size,
                              hipStream_t stream) {
    const float* x = (const float*)d_in[0];
    float* A = (float*)d_ws;   // dist^2 to nearest zero of x
    float* B = (float*)d_out;  // dist^2 to nearest nonzero of x
    float* out = (float*)d_out;

    sdt_scan_axis0<<<NN2 / 128, 128, 0, stream>>>(x, A, B);
    sdt_pass<1, false><<<1536, 256, 0, stream>>>(A, B, nullptr, nullptr);
    sdt_pass<2, false><<<768, 256, 0, stream>>>(A, nullptr, nullptr, nullptr);
    sdt_pass<2, true ><<<768, 256, 0, stream>>>(B, nullptr, A, out);
}

// Round 4
// 122.820 us; speedup vs baseline: 2.8995x; 1.3297x over previous
//
#include <hip/hip_runtime.h>

// Signed distance transform, N=192^3, exact separable EDT.
//   scan (axis 0): binary run-length scan -> u16 d^2 (65535 = INF marker)
//   axis 1/2: outward expansion min-plus: d_i = min_r f[i+-r] + r^2, ballot
//             early-exit at r with all d <= (r+2)^2 -> exact minimal trips.
//             r>38 -> full-line fallback (exactness guaranteed). In-place u16.
//   dispatch order: scan -> ax1(A) -> {ax2(A) | ax1(B)} merged -> ax2(B)+tanh.
// A16 = d^2 to nearest zero of x (ws), B16 = d^2 to nearest nonzero (ws+14MB).

typedef unsigned short u16;

#define NN    192
#define NN2   (192 * 192)
#define NN3   (192 * 192 * 192)

#define LINES 48
#define PADL  40
#define SROW  276        // 40 pad + 192 data + 44 pad (words); 16B-aligned rows
#define SENT  3.0e7f     // sentinel: keeps loop alive, never a final value

// ---------------------------------------------------------------------------
// Pass 1 (axis 0, stride NN2): binary input -> u16 squared run distances.
// ---------------------------------------------------------------------------
__global__ __launch_bounds__(128) void sdt_scan_axis0(const float* __restrict__ x,
                                                      u16* __restrict__ A,
                                                      u16* __restrict__ B) {
    __shared__ unsigned char nxF[NN * 128];
    __shared__ unsigned char nxB[NN * 128];
    const int t = threadIdx.x;
    const int L = blockIdx.x * 128 + t;

    unsigned int runF = 250u, runB = 250u;
    for (int i = NN - 1; i >= 0; --i) {
        float v = x[(size_t)L + (size_t)i * NN2];
        bool fg = (v != 0.0f);
        runB = fg ? 0u : (runB < 250u ? runB + 1u : 250u);
        runF = fg ? (runF < 250u ? runF + 1u : 250u) : 0u;
        nxB[i * 128 + t] = (unsigned char)runB;
        nxF[i * 128 + t] = (unsigned char)runF;
    }
    unsigned int rpF = 250u, rpB = 250u;
    for (int i = 0; i < NN; ++i) {
        unsigned int nB = nxB[i * 128 + t];
        unsigned int nF = nxF[i * 128 + t];
        rpB = (nB == 0u) ? 0u : (rpB < 250u ? rpB + 1u : 250u);
        rpF = (nF == 0u) ? 0u : (rpF < 250u ? rpF + 1u : 250u);
        unsigned int dB = rpB < nB ? rpB : nB;
        unsigned int dF = rpF < nF ? rpF : nF;
        A[(size_t)L + (size_t)i * NN2] = (dF >= 250u) ? (u16)65535u : (u16)(dF * dF);
        B[(size_t)L + (size_t)i * NN2] = (dB >= 250u) ? (u16)65535u : (u16)(dB * dB);
    }
}

// ---------------------------------------------------------------------------
// Full-line fallback for one line (rare; exactness guarantee).
// ---------------------------------------------------------------------------
__device__ __forceinline__ void full_line(const float* __restrict__ row, int lane,
                                          float& d0, float& d1, float& d2) {
    const float fi0 = (float)lane, fi1 = (float)(lane + 64), fi2 = (float)(lane + 128);
    float e0 = 3e38f, e1 = 3e38f, e2 = 3e38f;
    for (int jb = 0; jb < NN; jb += 4) {
        float4 gq = *(const float4*)(row + jb);
#pragma unroll
        for (int k = 0; k < 4; ++k) {
            float gk = (k == 0) ? gq.x : (k == 1) ? gq.y : (k == 2) ? gq.z : gq.w;
            float jf = (float)(jb + k);
            float t0 = jf - fi0, t1 = jf - fi1, t2 = jf - fi2;
            e0 = fminf(e0, fmaf(t0, t0, gk));
            e1 = fminf(e1, fmaf(t1, t1, gk));
            e2 = fminf(e2, fmaf(t2, t2, gk));
        }
    }
    d0 = fminf(d0, e0); d1 = fminf(d1, e1); d2 = fminf(d2, e2);
}

// ---------------------------------------------------------------------------
// One 48-line tile pass (in-place u16). AXIS=1: elem stride NN, lines contig.
// AXIS=2: elems contig, lines stride NN. FUSE: tanh epilogue (AXIS=2, B).
// ---------------------------------------------------------------------------
template<int AXIS, bool FUSE>
__device__ __forceinline__ void pass_tile(u16* __restrict__ f, int g,
                                          const u16* __restrict__ other,
                                          float* __restrict__ outp,
                                          float* lds) {
    const int tid = threadIdx.x;
    size_t base;
    if (AXIS == 1) base = (size_t)(g >> 2) * NN2 + (size_t)(g & 3) * LINES;
    else           base = (size_t)g * (LINES * NN);

    // sentinel pads
    for (int idx = tid; idx < LINES * 84; idx += 256) {
        int l = idx / 84, c = idx - l * 84;
        int word = (c < PADL) ? c : (c + NN);
        lds[l * SROW + word] = SENT;
    }
    // stage in (u16 -> float; 65535 -> SENT)
    if (AXIS == 1) {
        for (int idx = tid; idx < NN * (LINES / 4); idx += 256) {
            int j = idx / (LINES / 4), lp = idx - j * (LINES / 4);
            ushort4 v = *(const ushort4*)(f + base + (size_t)j * NN + 4 * lp);
            float g0 = (v.x == 65535u) ? SENT : (float)v.x;
            float g1 = (v.y == 65535u) ? SENT : (float)v.y;
            float g2 = (v.z == 65535u) ? SENT : (float)v.z;
            float g3 = (v.w == 65535u) ? SENT : (float)v.w;
            int a = PADL + j;
            lds[(4 * lp + 0) * SROW + a] = g0;
            lds[(4 * lp + 1) * SROW + a] = g1;
            lds[(4 * lp + 2) * SROW + a] = g2;
            lds[(4 * lp + 3) * SROW + a] = g3;
        }
    } else {
        for (int idx = tid; idx < LINES * (NN / 8); idx += 256) {
            int l = idx / (NN / 8), jp = idx - l * (NN / 8);
            const u16* p = f + base + (size_t)l * NN + 8 * jp;
            ushort4 v0 = *(const ushort4*)(p);
            ushort4 v1 = *(const ushort4*)(p + 4);
            float* q = lds + l * SROW + PADL + 8 * jp;
            float4 a0, a1;
            a0.x = (v0.x == 65535u) ? SENT : (float)v0.x;
            a0.y = (v0.y == 65535u) ? SENT : (float)v0.y;
            a0.z = (v0.z == 65535u) ? SENT : (float)v0.z;
            a0.w = (v0.w == 65535u) ? SENT : (float)v0.w;
            a1.x = (v1.x == 65535u) ? SENT : (float)v1.x;
            a1.y = (v1.y == 65535u) ? SENT : (float)v1.y;
            a1.z = (v1.z == 65535u) ? SENT : (float)v1.z;
            a1.w = (v1.w == 65535u) ? SENT : (float)v1.w;
            *(float4*)(q) = a0;
            *(float4*)(q + 4) = a1;
        }
    }
    __syncthreads();

    const int lane = tid & 63;
    const int w = tid >> 6;
    const int i1 = lane + 64, i2 = lane + 128;

    for (int pp = 0; pp < 6; ++pp) {
        float* rowa = lds + (w * 12 + 2 * pp) * SROW + PADL;
        float* rowb = rowa + SROW;
        float d0a = rowa[lane], d1a = rowa[i1], d2a = rowa[i2];
        float d0b = rowb[lane], d1b = rowb[i1], d2b = rowb[i2];

        int r = 1;
        bool conv = false;
        while (true) {
            float rr1 = (float)(r * r);
            float rr2 = (float)((r + 1) * (r + 1));
            {
                float la1 = rowa[lane - r - 1], la0 = rowa[lane - r];
                float ra0 = rowa[lane + r],     ra1 = rowa[lane + r + 1];
                d0a = fminf(d0a, fminf(la0 + rr1, la1 + rr2));
                d0a = fminf(d0a, fminf(ra0 + rr1, ra1 + rr2));
                float lb1 = rowa[i1 - r - 1], lb0 = rowa[i1 - r];
                float rb0 = rowa[i1 + r],     rb1 = rowa[i1 + r + 1];
                d1a = fminf(d1a, fminf(lb0 + rr1, lb1 + rr2));
                d1a = fminf(d1a, fminf(rb0 + rr1, rb1 + rr2));
                float lc1 = rowa[i2 - r - 1], lc0 = rowa[i2 - r];
                float rc0 = rowa[i2 + r],     rc1 = rowa[i2 + r + 1];
                d2a = fminf(d2a, fminf(lc0 + rr1, lc1 + rr2));
                d2a = fminf(d2a, fminf(rc0 + rr1, rc1 + rr2));
            }
            {
                float la1 = rowb[lane - r - 1], la0 = rowb[lane - r];
                float ra0 = rowb[lane + r],     ra1 = rowb[lane + r + 1];
                d0b = fminf(d0b, fminf(la0 + rr1, la1 + rr2));
                d0b = fminf(d0b, fminf(ra0 + rr1, ra1 + rr2));
                float lb1 = rowb[i1 - r - 1], lb0 = rowb[i1 - r];
                float rb0 = rowb[i1 + r],     rb1 = rowb[i1 + r + 1];
                d1b = fminf(d1b, fminf(lb0 + rr1, lb1 + rr2));
                d1b = fminf(d1b, fminf(rb0 + rr1, rb1 + rr2));
                float lc1 = rowb[i2 - r - 1], lc0 = rowb[i2 - r];
                float rc0 = rowb[i2 + r],     rc1 = rowb[i2 + r + 1];
                d2b = fminf(d2b, fminf(lc0 + rr1, lc1 + rr2));
                d2b = fminf(d2b, fminf(rc0 + rr1, rc1 + rr2));
            }
            float nrr = (float)((r + 2) * (r + 2));
            float m = fmaxf(fmaxf(fmaxf(d0a, d1a), fmaxf(d2a, d0b)), fmaxf(d1b, d2b));
            if (__all(m <= nrr)) { conv = true; break; }
            r += 2;
            if (r > 37) break;   // processed radii <= 38
        }
        if (!conv) {
            // remaining improvements need radius >= 39 -> only if d > 39^2
            float m = fmaxf(fmaxf(fmaxf(d0a, d1a), fmaxf(d2a, d0b)), fmaxf(d1b, d2b));
            if (__any(m > 1521.0f)) {
                full_line(rowa, lane, d0a, d1a, d2a);
                full_line(rowb, lane, d0b, d1b, d2b);
            }
        }
        // this wave owns these rows; its reads are complete (in-order DS)
        rowa[lane] = d0a; rowa[i1] = d1a; rowa[i2] = d2a;
        rowb[lane] = d0b; rowb[i1] = d1b; rowb[i2] = d2b;
    }
    __syncthreads();

    // stage out
    if (AXIS == 1) {
        for (int idx = tid; idx < NN * (LINES / 4); idx += 256) {
            int j = idx / (LINES / 4), lp = idx - j * (LINES / 4);
            int a = PADL + j;
            float g0 = lds[(4 * lp + 0) * SROW + a];
            float g1 = lds[(4 * lp + 1) * SROW + a];
            float g2 = lds[(4 * lp + 2) * SROW + a];
            float g3 = lds[(4 * lp + 3) * SROW + a];
            ushort4 v;
            v.x = (u16)(unsigned int)fminf(g0 + 0.5f, 65535.f);
            v.y = (u16)(unsigned int)fminf(g1 + 0.5f, 65535.f);
            v.z = (u16)(unsigned int)fminf(g2 + 0.5f, 65535.f);
            v.w = (u16)(unsigned int)fminf(g3 + 0.5f, 65535.f);
            *(ushort4*)(f + base + (size_t)j * NN + 4 * lp) = v;
        }
    } else if (!FUSE) {
        for (int idx = tid; idx < LINES * (NN / 8); idx += 256) {
            int l = idx / (NN / 8), jp = idx - l * (NN / 8);
            const float* q = lds + l * SROW + PADL + 8 * jp;
            float4 a0 = *(const float4*)(q);
            float4 a1 = *(const float4*)(q + 4);
            ushort4 v0, v1;
            v0.x = (u16)(unsigned int)(a0.x + 0.5f);
            v0.y = (u16)(unsigned int)(a0.y + 0.5f);
            v0.z = (u16)(unsigned int)(a0.z + 0.5f);
            v0.w = (u16)(unsigned int)(a0.w + 0.5f);
            v1.x = (u16)(unsigned int)(a1.x + 0.5f);
            v1.y = (u16)(unsigned int)(a1.y + 0.5f);
            v1.z = (u16)(unsigned int)(a1.z + 0.5f);
            v1.w = (u16)(unsigned int)(a1.w + 0.5f);
            u16* p = f + base + (size_t)l * NN + 8 * jp;
            *(ushort4*)(p) = v0;
            *(ushort4*)(p + 4) = v1;
        }
    } else {
        for (int idx = tid; idx < LINES * (NN / 8); idx += 256) {
            int l = idx / (NN / 8), jp = idx - l * (NN / 8);
            const float* q = lds + l * SROW + PADL + 8 * jp;
            size_t ga = base + (size_t)l * NN + 8 * jp;
            const u16* ap = other + ga;
            ushort4 av0 = *(const ushort4*)(ap);
            ushort4 av1 = *(const ushort4*)(ap + 4);
            float bq[8];
            *(float4*)(bq) = *(const float4*)(q);
            *(float4*)(bq + 4) = *(const float4*)(q + 4);
            float aq[8] = {(float)av0.x, (float)av0.y, (float)av0.z, (float)av0.w,
                           (float)av1.x, (float)av1.y, (float)av1.z, (float)av1.w};
            float rq[8];
#pragma unroll
            for (int k = 0; k < 8; ++k) {
                float xx = (sqrtf(aq[k]) - sqrtf(bq[k])) * 0.1f;
                float e = __expf(2.f * xx);
                rq[k] = 1.f - 2.f * __builtin_amdgcn_rcpf(e + 1.f);
            }
            *(float4*)(outp + ga) = *(float4*)(rq);
            *(float4*)(outp + ga + 4) = *(float4*)(rq + 4);
        }
    }
}

__global__ __launch_bounds__(256) void sdt_ax1A(u16* __restrict__ A) {
    __shared__ __align__(16) float lds[LINES * SROW];
    pass_tile<1, false>(A, blockIdx.x, nullptr, nullptr, lds);
}

// merged: g<768 -> axis2 on A (final A); g>=768 -> axis1 on B
__global__ __launch_bounds__(256) void sdt_mid(u16* __restrict__ A, u16* __restrict__ B) {
    __shared__ __align__(16) float lds[LINES * SROW];
    int g = blockIdx.x;
    if (g < 768) pass_tile<2, false>(A, g, nullptr, nullptr, lds);
    else         pass_tile<1, false>(B, g - 768, nullptr, nullptr, lds);
}

__global__ __launch_bounds__(256) void sdt_ax2Bf(u16* __restrict__ B,
                                                 const u16* __restrict__ A,
                                                 float* __restrict__ outp) {
    __shared__ __align__(16) float lds[LINES * SROW];
    pass_tile<2, true>(B, blockIdx.x, A, outp, lds);
}

extern "C" void kernel_launch(void* const* d_in, const int* in_sizes, int n_in,
                              void* d_out, int out_size, void* d_ws, size_t ws_size,
                              hipStream_t stream) {
    const float* x = (const float*)d_in[0];
    u16* A = (u16*)d_ws;                       // 14.2 MB
    u16* B = (u16*)((char*)d_ws + (size_t)NN3 * 2);  // 14.2 MB
    float* out = (float*)d_out;

    sdt_scan_axis0<<<NN2 / 128, 128, 0, stream>>>(x, A, B);
    sdt_ax1A<<<768, 256, 0, stream>>>(A);
    sdt_mid<<<1536, 256, 0, stream>>>(A, B);
    sdt_ax2Bf<<<768, 256, 0, stream>>>(B, A, out);
}

// Round 5
// 106.393 us; speedup vs baseline: 3.3472x; 1.1544x over previous
//
#include <hip/hip_runtime.h>

// Signed distance transform, N=192^3, exact separable EDT, packed-u16 pipeline.
//   scan (axis 0): binary run-length scan -> u16 d^2 (65535 = INF marker)
//   axis 1/2: outward expansion min-plus on PAIRS of lines packed lo/hi in one
//             u32 word; candidates via v_pk_add_u16 + v_pk_min_u16; ballot
//             early-exit when all d <= (r+2)^2; r>38 -> float full fallback.
//   dispatch: scan -> ax1(A) -> {ax1(B) | ax2(A)} merged -> ax2(B)+tanh.
// A = d^2 to nearest zero of x (ws), B = d^2 to nearest nonzero (ws+14MB).

typedef unsigned short u16;
typedef unsigned int   u32;
typedef u16 u16x2 __attribute__((ext_vector_type(2)));

#define NN    192
#define NN2   (192 * 192)
#define NN3   (192 * 192 * 192)

#define LINES 48
#define PAIRS 24
#define PADL  40
#define SROW  278            // words: 40 pad + 192 data + 46 pad
#define SENT16 50000
#define SENTPK 0xC350C350u

__device__ __forceinline__ u16x2 pkmin(u16x2 a, u16x2 b) { return __builtin_elementwise_min(a, b); }
__device__ __forceinline__ u16x2 pkmax(u16x2 a, u16x2 b) { return __builtin_elementwise_max(a, b); }

// ---------------------------------------------------------------------------
// Pass 1 (axis 0, stride NN2): binary input -> u16 squared run distances.
// ---------------------------------------------------------------------------
__global__ __launch_bounds__(128) void sdt_scan_axis0(const float* __restrict__ x,
                                                      u16* __restrict__ A,
                                                      u16* __restrict__ B) {
    __shared__ unsigned char nxF[NN * 128];
    __shared__ unsigned char nxB[NN * 128];
    const int t = threadIdx.x;
    const int L = blockIdx.x * 128 + t;

    unsigned int runF = 250u, runB = 250u;
    for (int i = NN - 1; i >= 0; --i) {
        float v = x[(size_t)L + (size_t)i * NN2];
        bool fg = (v != 0.0f);
        runB = fg ? 0u : (runB < 250u ? runB + 1u : 250u);
        runF = fg ? (runF < 250u ? runF + 1u : 250u) : 0u;
        nxB[i * 128 + t] = (unsigned char)runB;
        nxF[i * 128 + t] = (unsigned char)runF;
    }
    unsigned int rpF = 250u, rpB = 250u;
    for (int i = 0; i < NN; ++i) {
        unsigned int nB = nxB[i * 128 + t];
        unsigned int nF = nxF[i * 128 + t];
        rpB = (nB == 0u) ? 0u : (rpB < 250u ? rpB + 1u : 250u);
        rpF = (nF == 0u) ? 0u : (rpF < 250u ? rpF + 1u : 250u);
        unsigned int dB = rpB < nB ? rpB : nB;
        unsigned int dF = rpF < nF ? rpF : nF;
        A[(size_t)L + (size_t)i * NN2] = (dF >= 250u) ? (u16)65535u : (u16)(dF * dF);
        B[(size_t)L + (size_t)i * NN2] = (dB >= 250u) ? (u16)65535u : (u16)(dB * dB);
    }
}

// ---------------------------------------------------------------------------
// One 48-line tile pass, packed pairs, in-place u16.
// AXIS=1: elem stride NN, lines contiguous (pair = adjacent x).
// AXIS=2: elems contiguous, lines stride NN (pair = adjacent y).
// FUSE: tanh epilogue (AXIS=2 on B, reads final A, writes float out).
// ---------------------------------------------------------------------------
template<int AXIS, bool FUSE>
__device__ __forceinline__ void pass_tile(u16* __restrict__ f, int g,
                                          const u16* __restrict__ other,
                                          float* __restrict__ outp,
                                          u32* ldsw) {
    const int tid = threadIdx.x;
    size_t base;
    if (AXIS == 1) base = (size_t)(g >> 2) * NN2 + (size_t)(g & 3) * LINES;
    else           base = (size_t)g * (LINES * NN);

    const u16x2 sentv = {(u16)SENT16, (u16)SENT16};

    // sentinel pads: words [0,40) and [232,278) per pair row
    for (int idx = tid; idx < PAIRS * 86; idx += 256) {
        int p = idx / 86, c = idx - p * 86;
        int word = (c < PADL) ? c : (c + NN);
        ldsw[p * SROW + word] = SENTPK;
    }
    // stage in (packed; remap 65535 -> 50000 via pk_min)
    if (AXIS == 1) {
        for (int idx = tid; idx < NN * (PAIRS / 2); idx += 256) {
            int j = idx / (PAIRS / 2), pp = idx - j * (PAIRS / 2);
            uint2 v = *(const uint2*)(f + base + (size_t)j * NN + 4 * pp);
            u16x2 a = pkmin(__builtin_bit_cast(u16x2, v.x), sentv);
            u16x2 b = pkmin(__builtin_bit_cast(u16x2, v.y), sentv);
            ldsw[(2 * pp) * SROW + PADL + j]     = __builtin_bit_cast(u32, a);
            ldsw[(2 * pp + 1) * SROW + PADL + j] = __builtin_bit_cast(u32, b);
        }
    } else {
        for (int idx = tid; idx < PAIRS * (NN / 4); idx += 256) {
            int p = idx / (NN / 4), jp = idx - p * (NN / 4);
            const u16* p0 = f + base + (size_t)(2 * p) * NN + 4 * jp;
            ushort4 v0 = *(const ushort4*)(p0);
            ushort4 v1 = *(const ushort4*)(p0 + NN);
            u16x2 w0 = {v0.x, v1.x}, w1 = {v0.y, v1.y};
            u16x2 w2 = {v0.z, v1.z}, w3 = {v0.w, v1.w};
            u32* q = ldsw + p * SROW + PADL + 4 * jp;
            uint2 s0, s1;
            s0.x = __builtin_bit_cast(u32, pkmin(w0, sentv));
            s0.y = __builtin_bit_cast(u32, pkmin(w1, sentv));
            s1.x = __builtin_bit_cast(u32, pkmin(w2, sentv));
            s1.y = __builtin_bit_cast(u32, pkmin(w3, sentv));
            *(uint2*)(q) = s0;
            *(uint2*)(q + 2) = s1;
        }
    }
    __syncthreads();

    const int lane = tid & 63;
    const int w = tid >> 6;
    const int i0 = lane, i1 = lane + 64, i2 = lane + 128;

    for (int pp = 0; pp < 6; ++pp) {
        u16x2* rp = (u16x2*)(ldsw + (w * 6 + pp) * SROW + PADL);
        u16x2 d0 = rp[i0], d1 = rp[i1], d2 = rp[i2];

        int r = 1;
        bool conv = false;
        while (true) {
            u16 rr1 = (u16)(r * r), rr2 = (u16)((r + 1) * (r + 1));
            u16x2 q1 = {rr1, rr1}, q2 = {rr2, rr2};
            {
                u16x2 l1 = rp[i0 - r - 1], l0 = rp[i0 - r];
                u16x2 r0 = rp[i0 + r],     r1v = rp[i0 + r + 1];
                d0 = pkmin(d0, pkmin(l0 + q1, l1 + q2));
                d0 = pkmin(d0, pkmin(r0 + q1, r1v + q2));
            }
            {
                u16x2 l1 = rp[i1 - r - 1], l0 = rp[i1 - r];
                u16x2 r0 = rp[i1 + r],     r1v = rp[i1 + r + 1];
                d1 = pkmin(d1, pkmin(l0 + q1, l1 + q2));
                d1 = pkmin(d1, pkmin(r0 + q1, r1v + q2));
            }
            {
                u16x2 l1 = rp[i2 - r - 1], l0 = rp[i2 - r];
                u16x2 r0 = rp[i2 + r],     r1v = rp[i2 + r + 1];
                d2 = pkmin(d2, pkmin(l0 + q1, l1 + q2));
                d2 = pkmin(d2, pkmin(r0 + q1, r1v + q2));
            }
            u16x2 m = pkmax(pkmax(d0, d1), d2);
            unsigned mm = (m.x > m.y) ? m.x : m.y;
            unsigned thr = (unsigned)((r + 2) * (r + 2));
            if (__all(mm <= thr)) { conv = true; break; }
            r += 2;
            if (r > 37) break;   // processed radii <= 38
        }
        if (!conv) {
            u16x2 m = pkmax(pkmax(d0, d1), d2);
            unsigned mm = (m.x > m.y) ? m.x : m.y;
            if (__any(mm > 1521u)) {
                // exact full-line fallback (float domain), both halves
                const float fi0 = (float)i0, fi1 = (float)i1, fi2 = (float)i2;
                float e0l = 3e38f, e0h = 3e38f, e1l = 3e38f, e1h = 3e38f;
                float e2l = 3e38f, e2h = 3e38f;
                for (int j = 0; j < NN; ++j) {
                    u16x2 gv = rp[j];
                    float gl = (float)gv.x, gh = (float)gv.y;
                    float jf = (float)j;
                    float t0 = jf - fi0, t1 = jf - fi1, t2 = jf - fi2;
                    float s0 = t0 * t0, s1 = t1 * t1, s2 = t2 * t2;
                    e0l = fminf(e0l, s0 + gl); e0h = fminf(e0h, s0 + gh);
                    e1l = fminf(e1l, s1 + gl); e1h = fminf(e1h, s1 + gh);
                    e2l = fminf(e2l, s2 + gl); e2h = fminf(e2h, s2 + gh);
                }
                d0.x = (u16)fminf((float)d0.x, e0l); d0.y = (u16)fminf((float)d0.y, e0h);
                d1.x = (u16)fminf((float)d1.x, e1l); d1.y = (u16)fminf((float)d1.y, e1h);
                d2.x = (u16)fminf((float)d2.x, e2l); d2.y = (u16)fminf((float)d2.y, e2h);
            }
        }
        // wave owns this pair row; its reads completed (in-order DS)
        rp[i0] = d0; rp[i1] = d1; rp[i2] = d2;
    }
    __syncthreads();

    // stage out
    if (AXIS == 1) {
        for (int idx = tid; idx < NN * (PAIRS / 2); idx += 256) {
            int j = idx / (PAIRS / 2), pp = idx - j * (PAIRS / 2);
            uint2 v;
            v.x = ldsw[(2 * pp) * SROW + PADL + j];
            v.y = ldsw[(2 * pp + 1) * SROW + PADL + j];
            *(uint2*)(f + base + (size_t)j * NN + 4 * pp) = v;
        }
    } else if (!FUSE) {
        for (int idx = tid; idx < PAIRS * (NN / 4); idx += 256) {
            int p = idx / (NN / 4), jp = idx - p * (NN / 4);
            const u32* q = ldsw + p * SROW + PADL + 4 * jp;
            u16x2 w0 = __builtin_bit_cast(u16x2, q[0]);
            u16x2 w1 = __builtin_bit_cast(u16x2, q[1]);
            u16x2 w2 = __builtin_bit_cast(u16x2, q[2]);
            u16x2 w3 = __builtin_bit_cast(u16x2, q[3]);
            ushort4 lo = {w0.x, w1.x, w2.x, w3.x};
            ushort4 hi = {w0.y, w1.y, w2.y, w3.y};
            u16* p0 = f + base + (size_t)(2 * p) * NN + 4 * jp;
            *(ushort4*)(p0) = lo;
            *(ushort4*)(p0 + NN) = hi;
        }
    } else {
        for (int idx = tid; idx < PAIRS * (NN / 4); idx += 256) {
            int p = idx / (NN / 4), jp = idx - p * (NN / 4);
            const u32* q = ldsw + p * SROW + PADL + 4 * jp;
            u16x2 w0 = __builtin_bit_cast(u16x2, q[0]);
            u16x2 w1 = __builtin_bit_cast(u16x2, q[1]);
            u16x2 w2 = __builtin_bit_cast(u16x2, q[2]);
            u16x2 w3 = __builtin_bit_cast(u16x2, q[3]);
            size_t g0 = base + (size_t)(2 * p) * NN + 4 * jp;
            ushort4 a0 = *(const ushort4*)(other + g0);
            ushort4 a1 = *(const ushort4*)(other + g0 + NN);
            float bl[4] = {(float)w0.x, (float)w1.x, (float)w2.x, (float)w3.x};
            float bh[4] = {(float)w0.y, (float)w1.y, (float)w2.y, (float)w3.y};
            float al[4] = {(float)a0.x, (float)a0.y, (float)a0.z, (float)a0.w};
            float ah[4] = {(float)a1.x, (float)a1.y, (float)a1.z, (float)a1.w};
            float rl[4], rh[4];
#pragma unroll
            for (int k = 0; k < 4; ++k) {
                float xl = (sqrtf(al[k]) - sqrtf(bl[k])) * 0.1f;
                float el = __expf(2.f * xl);
                rl[k] = 1.f - 2.f * __builtin_amdgcn_rcpf(el + 1.f);
                float xh = (sqrtf(ah[k]) - sqrtf(bh[k])) * 0.1f;
                float eh = __expf(2.f * xh);
                rh[k] = 1.f - 2.f * __builtin_amdgcn_rcpf(eh + 1.f);
            }
            *(float4*)(outp + g0) = *(float4*)(rl);
            *(float4*)(outp + g0 + NN) = *(float4*)(rh);
        }
    }
}

__global__ __launch_bounds__(256) void sdt_ax1A(u16* __restrict__ A) {
    __shared__ __align__(16) u32 ldsw[PAIRS * SROW]; // 26,688 B -> 6 blocks/CU
    pass_tile<1, false>(A, blockIdx.x, nullptr, nullptr, ldsw);
}

// merged: g<768 -> axis1 on B (heavy); g>=768 -> axis2 on A (light, final A)
__global__ __launch_bounds__(256) void sdt_mid(u16* __restrict__ A, u16* __restrict__ B) {
    __shared__ __align__(16) u32 ldsw[PAIRS * SROW];
    int g = blockIdx.x;
    if (g < 768) pass_tile<1, false>(B, g, nullptr, nullptr, ldsw);
    else         pass_tile<2, false>(A, g - 768, nullptr, nullptr, ldsw);
}

__global__ __launch_bounds__(256) void sdt_ax2Bf(u16* __restrict__ B,
                                                 const u16* __restrict__ A,
                                                 float* __restrict__ outp) {
    __shared__ __align__(16) u32 ldsw[PAIRS * SROW];
    pass_tile<2, true>(B, blockIdx.x, A, outp, ldsw);
}

extern "C" void kernel_launch(void* const* d_in, const int* in_sizes, int n_in,
                              void* d_out, int out_size, void* d_ws, size_t ws_size,
                              hipStream_t stream) {
    const float* x = (const float*)d_in[0];
    u16* A = (u16*)d_ws;
    u16* B = (u16*)((char*)d_ws + (size_t)NN3 * 2);
    float* out = (float*)d_out;

    sdt_scan_axis0<<<NN2 / 128, 128, 0, stream>>>(x, A, B);
    sdt_ax1A<<<768, 256, 0, stream>>>(A);
    sdt_mid<<<1536, 256, 0, stream>>>(A, B);
    sdt_ax2Bf<<<768, 256, 0, stream>>>(B, A, out);
}